// Round 5
// baseline (9935.163 us; speedup 1.0000x reference)
//
#include <hip/hip_runtime.h>
#include <hip/hip_bf16.h>
#include <math.h>

// problem constants
static const int B2   = 2;     // batch
static const int TT   = 16;    // frames
static const int NTK  = 1024;  // pose tokens (M==N)
static const int CTK  = 256;   // context tokens per frame
static const int QD   = 320;   // query dim
static const int INNR = 512;   // inner dim
static const int CD   = 1024;  // context dim
#define SCALE_ 0.125f

#define TS 64
#define KT 16

#define GEMM_VARS \
  const int tx = threadIdx.x, ty = threadIdx.y; \
  const int tid = ty*16+tx; (void)tid;

#define GEMM_INNER \
    __syncthreads(); \
    _Pragma("unroll") \
    for (int kk=0; kk<KT; kk++){ \
      float aR[4], bR[4]; \
      _Pragma("unroll") for(int i=0;i<4;i++) aR[i]=As[kk][ty*4+i]; \
      _Pragma("unroll") for(int j=0;j<4;j++) bR[j]=Bs[kk][tx*4+j]; \
      _Pragma("unroll") for(int i=0;i<4;i++){ \
        _Pragma("unroll") for(int j=0;j<4;j++){ acc[i][j] = fmaf(aR[i],bR[j],acc[i][j]); } } \
    } \
    __syncthreads();

// ---------------- NN GEMM, all f32: C[M,N] = A[M,K] @ B[K,N] ----------------
__global__ void __launch_bounds__(256) k_gemm_ab(
    const float* __restrict__ A, const float* __restrict__ Bm, float* __restrict__ C,
    int K, int lda, int ldb, int ldc){
  __shared__ float As[KT][TS+1], Bs[KT][TS+1];
  GEMM_VARS
  float acc[4][4] = {{0}};
  const float* Ab = A + (size_t)(blockIdx.y*TS)*lda;
  const float* Bb = Bm + blockIdx.x*TS;
  for(int k0=0;k0<K;k0+=KT){
    #pragma unroll
    for(int i=0;i<4;i++){ int e=tid+i*256; int m=e>>4; int kk=e&15;
      As[kk][m]=Ab[(size_t)m*lda + k0+kk]; }
    #pragma unroll
    for(int i=0;i<4;i++){ int e=tid+i*256; int kk=e>>6; int nn=e&63;
      Bs[kk][nn]=Bb[(size_t)(k0+kk)*ldb + nn]; }
    GEMM_INNER
  }
  float* Cb = C + (size_t)(blockIdx.y*TS)*ldc + blockIdx.x*TS;
  #pragma unroll
  for(int i=0;i<4;i++)
    #pragma unroll
    for(int j=0;j<4;j++) Cb[(size_t)(ty*4+i)*ldc + tx*4+j] = acc[i][j];
}

// ---------------- a_tok chunk: atokC[z] = pose_t[pt] @ Wa, z in [0,4) ----------------
__global__ void __launch_bounds__(256) k_gemm_atok(
    const float* __restrict__ pose, const float* __restrict__ Wa, float* __restrict__ atokC, int ch){
  __shared__ float As[KT][TS+1], Bs[KT][TS+1];
  GEMM_VARS
  float acc[4][4] = {{0}};
  const int z = blockIdx.z, pt = ch*4+z, b = pt>>4, t = pt&15;
  const int mBase = blockIdx.y*TS, nBase = blockIdx.x*TS;
  for(int k0=0;k0<QD;k0+=KT){
    #pragma unroll
    for(int i=0;i<4;i++){ int e=tid+i*256; int m=e&63; int kk=e>>6;
      As[kk][m]=pose[ ((size_t)(b*QD + k0+kk)*TT + t)*NTK + mBase + m ]; }
    #pragma unroll
    for(int i=0;i<4;i++){ int e=tid+i*256; int kk=e>>6; int nn=e&63;
      Bs[kk][nn]=Wa[(size_t)(k0+kk)*INNR + nBase+nn]; }
    GEMM_INNER
  }
  float* Cb = atokC + ((size_t)z*NTK + mBase)*INNR + nBase;
  #pragma unroll
  for(int i=0;i<4;i++)
    #pragma unroll
    for(int j=0;j<4;j++) Cb[(size_t)(ty*4+i)*INNR + tx*4+j] = acc[i][j];
}

// ---------------- agent logits chunk: NT GEMM + scale + bias ----------------
// lgC[(zp*2+c)][m][nc] = SCALE*dot(atokC[zp,m,:], kf[b, nc*2+c, :]) + abias[m][nc]
__global__ void __launch_bounds__(256) k_logits(
    const float* __restrict__ atokC, const float* __restrict__ kbuf,
    const float* __restrict__ abias, float* __restrict__ lgC, int ch){
  __shared__ float As[KT][TS+1], Bs[KT][TS+1];
  GEMM_VARS
  float acc[4][4] = {{0}};
  const int z=blockIdx.z, zp=z>>1, c=z&1, pt=ch*4+zp, b=pt>>4;
  const int mBase=blockIdx.y*TS, nBase=blockIdx.x*TS;   // nBase over nc
  const float* Ab = atokC + ((size_t)zp*NTK + mBase)*INNR;
  const float* Bb = kbuf + ((size_t)(b*512) + (size_t)nBase*2 + c)*INNR;
  for(int k0=0;k0<INNR;k0+=KT){
    #pragma unroll
    for(int i=0;i<4;i++){ int e=tid+i*256; int r=e>>4; int kk=e&15;
      As[kk][r]=Ab[(size_t)r*INNR + k0+kk];
      Bs[kk][r]=Bb[(size_t)r*(2*INNR) + k0+kk]; }
    GEMM_INNER
  }
  float* Cb = lgC + ((size_t)(zp*2+c)*NTK + mBase)*CTK + nBase;
  const float* bb = abias + (size_t)mBase*CTK + nBase;
  #pragma unroll
  for(int i=0;i<4;i++)
    #pragma unroll
    for(int j=0;j<4;j++){
      size_t o=(size_t)(ty*4+i)*CTK + tx*4+j;
      Cb[o] = acc[i][j]*SCALE_ + bb[o];
    }
}

// ---------------- softmax over rows of 256 ----------------
__global__ void k_softmax256(float* __restrict__ buf){
  __shared__ float red[8];
  const int tid=threadIdx.x;
  size_t row=blockIdx.x;
  float x = buf[row*256+tid];
  float m = x;
  #pragma unroll
  for(int o=32;o;o>>=1) m=fmaxf(m,__shfl_down(m,o));
  if((tid&63)==0) red[tid>>6]=m;
  __syncthreads();
  if(tid==0) red[4]=fmaxf(fmaxf(red[0],red[1]),fmaxf(red[2],red[3]));
  __syncthreads();
  float M=red[4];
  float e=__expf(x-M);
  float s=e;
  #pragma unroll
  for(int o=32;o;o>>=1) s+=__shfl_down(s,o);
  if((tid&63)==0) red[tid>>6]=s;
  __syncthreads();
  if(tid==0) red[5]=red[0]+red[1]+red[2]+red[3];
  __syncthreads();
  buf[row*256+tid] = e/red[5];
}

// ---------------- softmax over rows of 1024 ----------------
__global__ void k_softmax1024(float* __restrict__ buf){
  __shared__ float red[8];
  const int tid=threadIdx.x;
  size_t row=blockIdx.x;
  float4* p = (float4*)(buf + row*1024);
  float4 v = p[tid];
  float m = fmaxf(fmaxf(v.x,v.y),fmaxf(v.z,v.w));
  #pragma unroll
  for(int o=32;o;o>>=1) m=fmaxf(m,__shfl_down(m,o));
  if((tid&63)==0) red[tid>>6]=m;
  __syncthreads();
  if(tid==0) red[4]=fmaxf(fmaxf(red[0],red[1]),fmaxf(red[2],red[3]));
  __syncthreads();
  float M=red[4];
  v.x=__expf(v.x-M); v.y=__expf(v.y-M); v.z=__expf(v.z-M); v.w=__expf(v.w-M);
  float s=v.x+v.y+v.z+v.w;
  #pragma unroll
  for(int o=32;o;o>>=1) s+=__shfl_down(s,o);
  if((tid&63)==0) red[tid>>6]=s;
  __syncthreads();
  if(tid==0) red[5]=red[0]+red[1]+red[2]+red[3];
  __syncthreads();
  float inv=1.0f/red[5];
  v.x*=inv; v.y*=inv; v.z*=inv; v.w*=inv;
  p[tid]=v;
}

// ---------------- PV chunk with max over frames c ----------------
__global__ void __launch_bounds__(256) k_pvmax(
    const float* __restrict__ lgC, const float* __restrict__ vbuf,
    float* __restrict__ akvC, int ch){
  __shared__ float As[KT][TS+1], Bs[KT][TS+1];
  GEMM_VARS
  const int zp=blockIdx.z, pt=ch*4+zp, b=pt>>4;
  const int mBase=blockIdx.y*TS, nBase=blockIdx.x*TS;
  float best[4][4];
  for(int c=0;c<2;c++){
    float acc[4][4] = {{0}};
    const float* Ab = lgC + ((size_t)(zp*2+c)*NTK + mBase)*CTK;
    const float* Bb = vbuf + (size_t)(b*2+c)*CTK*INNR + nBase;
    for(int k0=0;k0<CTK;k0+=KT){
      #pragma unroll
      for(int i=0;i<4;i++){ int e=tid+i*256; int m=e>>4; int kk=e&15;
        As[kk][m]=Ab[(size_t)m*CTK + k0+kk]; }
      #pragma unroll
      for(int i=0;i<4;i++){ int e=tid+i*256; int kk=e>>6; int nn=e&63;
        Bs[kk][nn]=Bb[(size_t)(k0+kk)*INNR + nn]; }
      GEMM_INNER
    }
    #pragma unroll
    for(int i=0;i<4;i++)
      #pragma unroll
      for(int j=0;j<4;j++) best[i][j] = c ? fmaxf(best[i][j],acc[i][j]) : acc[i][j];
  }
  float* Cb = akvC + ((size_t)zp*NTK + mBase)*INNR + nBase;
  #pragma unroll
  for(int i=0;i<4;i++)
    #pragma unroll
    for(int j=0;j<4;j++) Cb[(size_t)(ty*4+i)*INNR + tx*4+j] = best[i][j];
}

// ---------------- depthwise 3x3 conv (SAME) + max over frames ----------------
__global__ void k_conv(const float* __restrict__ vbuf, const float* __restrict__ w3,
                       const float* __restrict__ wb, float* __restrict__ vm){
  int idx = blockIdx.x*256+threadIdx.x;
  if(idx >= B2*CTK*INNR) return;
  int e = idx & 511, hw = (idx>>9)&255, b = idx>>17;
  int h = hw>>4, w = hw&15;
  float wt[9];
  #pragma unroll
  for(int q=0;q<9;q++) wt[q]=w3[e*9+q];
  float bias = wb[e];
  float best=0.f;
  for(int c=0;c<2;c++){
    float s = bias;
    #pragma unroll
    for(int dy=-1;dy<=1;dy++)
      #pragma unroll
      for(int dx=-1;dx<=1;dx++){
        int hh=h+dy, ww=w+dx;
        if(hh>=0&&hh<16&&ww>=0&&ww<16)
          s += wt[(dy+1)*3+(dx+1)]*vbuf[((size_t)(b*2+c)*CTK + hh*16+ww)*INNR + e];
      }
    best = c ? fmaxf(best,s) : s;
  }
  vm[((size_t)b*CTK + hw)*INNR + e] = best;
}

// ---------------- bilinear x2 upsample (half-pixel, edge clamp) ----------------
__device__ __forceinline__ void up_wt(int i, int& j0, int& j1, float& w){
  float s = 0.5f*i - 0.25f;
  float f = floorf(s);
  w = s - f;
  int a = (int)f;
  j0 = min(15, max(0, a));
  j1 = min(15, max(0, a+1));
}
__global__ void k_up(const float* __restrict__ vm, float* __restrict__ vt){
  int idx = blockIdx.x*256+threadIdx.x;
  if(idx >= B2*NTK*INNR) return;
  int e = idx & 511, n = (idx>>9)&1023, b = idx>>19;
  int hm = n>>5, wm = n&31;
  int h0,h1,w0,w1; float fh,fw;
  up_wt(hm,h0,h1,fh); up_wt(wm,w0,w1,fw);
  const float* base = vm + (size_t)b*CTK*INNR + e;
  float v00=base[(size_t)(h0*16+w0)*INNR], v01=base[(size_t)(h0*16+w1)*INNR];
  float v10=base[(size_t)(h1*16+w0)*INNR], v11=base[(size_t)(h1*16+w1)*INNR];
  vt[((size_t)b*NTK+n)*INNR+e] = (1.f-fh)*((1.f-fw)*v00+fw*v01) + fh*((1.f-fw)*v10+fw*v11);
}

// ---------------- LayerNorm row stats (mean, rstd) over 320 ----------------
__global__ void k_lnstats(const float* __restrict__ hs, float* __restrict__ st){
  size_t r = blockIdx.x;
  int lane = threadIdx.x;
  float s=0.f, s2=0.f;
  #pragma unroll
  for(int j=0;j<5;j++){ float v=hs[r*QD + j*64 + lane]; s+=v; s2+=v*v; }
  #pragma unroll
  for(int o=32;o;o>>=1){ s+=__shfl_down(s,o); s2+=__shfl_down(s2,o); }
  if(lane==0){
    float mu=s*(1.f/320.f);
    float var=s2*(1.f/320.f)-mu*mu;
    st[2*r]=mu; st[2*r+1]=rsqrtf(var+1e-5f);
  }
}

// ---------------- q chunk = LN(hs[row0..row0+4096)) @ Wq ----------------
__global__ void __launch_bounds__(256) k_gemm_qln(
    const float* __restrict__ hs, const float* __restrict__ st,
    const float* __restrict__ nw, const float* __restrict__ nb,
    const float* __restrict__ Wq, float* __restrict__ qC, int row0){
  __shared__ float As[KT][TS+1], Bs[KT][TS+1];
  GEMM_VARS
  float acc[4][4] = {{0}};
  const int mBase=blockIdx.y*TS, nBase=blockIdx.x*TS;
  for(int k0=0;k0<QD;k0+=KT){
    #pragma unroll
    for(int i=0;i<4;i++){ int e=tid+i*256; int m=e>>4; int kk=e&15;
      int row=row0+mBase+m, col=k0+kk;
      As[kk][m]=(hs[(size_t)row*QD+col]-st[2*row])*st[2*row+1]*nw[col]+nb[col]; }
    #pragma unroll
    for(int i=0;i<4;i++){ int e=tid+i*256; int kk=e>>6; int nn=e&63;
      Bs[kk][nn]=Wq[(size_t)(k0+kk)*INNR + nBase+nn]; }
    GEMM_INNER
  }
  float* Cb = qC + (size_t)mBase*INNR + nBase;
  #pragma unroll
  for(int i=0;i<4;i++)
    #pragma unroll
    for(int j=0;j<4;j++) Cb[(size_t)(ty*4+i)*INNR + tx*4+j] = acc[i][j];
}

// ---------------- query attention logits (NT) + scale + qbias ----------------
__global__ void __launch_bounds__(256) k_aql(
    const float* __restrict__ qC, const float* __restrict__ atokC,
    const float* __restrict__ qbias, float* __restrict__ D){
  __shared__ float As[KT][TS+1], Bs[KT][TS+1];
  GEMM_VARS
  float acc[4][4] = {{0}};
  const int z=blockIdx.z;
  const int nBase=blockIdx.y*TS;   // query rows
  const int mBase=blockIdx.x*TS;   // agent cols
  const float* Ab = qC    + ((size_t)z*NTK + nBase)*INNR;
  const float* Bb = atokC + ((size_t)z*NTK + mBase)*INNR;
  for(int k0=0;k0<INNR;k0+=KT){
    #pragma unroll
    for(int i=0;i<4;i++){ int e=tid+i*256; int r=e>>4; int kk=e&15;
      As[kk][r]=Ab[(size_t)r*INNR + k0+kk];
      Bs[kk][r]=Bb[(size_t)r*INNR + k0+kk]; }
    GEMM_INNER
  }
  float* Cb = D + ((size_t)z*NTK + nBase)*NTK + mBase;
  const float* bb = qbias + (size_t)nBase*NTK + mBase;
  #pragma unroll
  for(int i=0;i<4;i++)
    #pragma unroll
    for(int j=0;j<4;j++){
      size_t o=(size_t)(ty*4+i)*NTK + tx*4+j;
      Cb[o] = acc[i][j]*SCALE_ + bb[o];
    }
}

// ---------------- x chunk = aq @ akvC + v_tok ----------------
__global__ void __launch_bounds__(256) k_aqpv(
    const float* __restrict__ D, const float* __restrict__ akvC,
    const float* __restrict__ vt, float* __restrict__ xC, int ch){
  __shared__ float As[KT][TS+1], Bs[KT][TS+1];
  GEMM_VARS
  float acc[4][4] = {{0}};
  const int z=blockIdx.z, pt=ch*4+z, b=pt>>4;
  const int nBase=blockIdx.y*TS;   // query rows
  const int eBase=blockIdx.x*TS;
  const float* Ab = D    + ((size_t)z*NTK + nBase)*NTK;
  const float* Bb = akvC + (size_t)z*NTK*INNR + eBase;
  for(int k0=0;k0<NTK;k0+=KT){
    #pragma unroll
    for(int i=0;i<4;i++){ int e=tid+i*256; int m=e>>4; int kk=e&15;
      As[kk][m]=Ab[(size_t)m*NTK + k0+kk]; }
    #pragma unroll
    for(int i=0;i<4;i++){ int e=tid+i*256; int kk=e>>6; int nn=e&63;
      Bs[kk][nn]=Bb[(size_t)(k0+kk)*INNR + nn]; }
    GEMM_INNER
  }
  float* Cb = xC + ((size_t)z*NTK + nBase)*INNR + eBase;
  const float* vb = vt + ((size_t)b*NTK + nBase)*INNR + eBase;
  #pragma unroll
  for(int i=0;i<4;i++)
    #pragma unroll
    for(int j=0;j<4;j++){
      size_t o=(size_t)(ty*4+i)*INNR + tx*4+j;
      Cb[o] = acc[i][j] + vb[o];
    }
}

// ---------------- hs[row0..row0+4096) += xC @ Wo ----------------
__global__ void __launch_bounds__(256) k_wo(
    const float* __restrict__ xC, const float* __restrict__ Wo,
    float* __restrict__ hs, int row0){
  __shared__ float As[KT][TS+1], Bs[KT][TS+1];
  GEMM_VARS
  float acc[4][4] = {{0}};
  const int mBase=blockIdx.y*TS, nBase=blockIdx.x*TS;
  const float* Ab = xC + (size_t)mBase*INNR;
  for(int k0=0;k0<INNR;k0+=KT){
    #pragma unroll
    for(int i=0;i<4;i++){ int e=tid+i*256; int m=e>>4; int kk=e&15;
      As[kk][m]=Ab[(size_t)m*INNR + k0+kk]; }
    #pragma unroll
    for(int i=0;i<4;i++){ int e=tid+i*256; int kk=e>>6; int nn=e&63;
      Bs[kk][nn]=Wo[(size_t)(k0+kk)*QD + nBase+nn]; }
    GEMM_INNER
  }
  float* Cb = hs + (size_t)(row0+mBase)*QD + nBase;
  #pragma unroll
  for(int i=0;i<4;i++)
    #pragma unroll
    for(int j=0;j<4;j++){
      size_t o=(size_t)(ty*4+i)*QD + tx*4+j;
      Cb[o] = Cb[o] + acc[i][j];
    }
}

// ---------------- FF1 chunk: G = a * gelu(g), rows [row0, row0+4096) ----------------
__global__ void __launch_bounds__(256) k_ff1(
    const float* __restrict__ hs, const float* __restrict__ st,
    const float* __restrict__ lw, const float* __restrict__ lb,
    const float* __restrict__ W1, const float* __restrict__ b1,
    float* __restrict__ G, int row0){
  __shared__ float As[KT][TS+1], Ba[KT][TS+1], Bg[KT][TS+1];
  const int tx = threadIdx.x, ty = threadIdx.y;
  const int tid = ty*16+tx;
  float accA[4][4] = {{0}}, accG[4][4] = {{0}};
  const int mBase=blockIdx.y*TS, nBase=blockIdx.x*TS;   // n in [0,1280)
  for(int k0=0;k0<QD;k0+=KT){
    #pragma unroll
    for(int i=0;i<4;i++){ int e=tid+i*256; int m=e>>4; int kk=e&15;
      int row=row0+mBase+m, col=k0+kk;
      As[kk][m]=(hs[(size_t)row*QD+col]-st[2*row])*st[2*row+1]*lw[col]+lb[col]; }
    #pragma unroll
    for(int i=0;i<4;i++){ int e=tid+i*256; int kk=e>>6; int nn=e&63;
      Ba[kk][nn]=W1[(size_t)(k0+kk)*2560 + nBase+nn];
      Bg[kk][nn]=W1[(size_t)(k0+kk)*2560 + 1280 + nBase+nn]; }
    __syncthreads();
    #pragma unroll
    for (int kk=0; kk<KT; kk++){
      float aR[4], bA[4], bG[4];
      #pragma unroll
      for(int i=0;i<4;i++) aR[i]=As[kk][ty*4+i];
      #pragma unroll
      for(int j=0;j<4;j++){ bA[j]=Ba[kk][tx*4+j]; bG[j]=Bg[kk][tx*4+j]; }
      #pragma unroll
      for(int i=0;i<4;i++)
        #pragma unroll
        for(int j=0;j<4;j++){
          accA[i][j] = fmaf(aR[i],bA[j],accA[i][j]);
          accG[i][j] = fmaf(aR[i],bG[j],accG[i][j]);
        }
    }
    __syncthreads();
  }
  #pragma unroll
  for(int i=0;i<4;i++)
    #pragma unroll
    for(int j=0;j<4;j++){
      int n = nBase+tx*4+j;
      float a = accA[i][j] + b1[n];
      float g = accG[i][j] + b1[1280+n];
      G[(size_t)(mBase+ty*4+i)*1280 + n] = a*0.5f*g*(1.0f+erff(g*0.70710678f));
    }
}

// ---------------- FF2 chunk: hs = G @ ff_w2 + b2 + hs  (in place, hs==d_out) ----------------
__global__ void __launch_bounds__(256) k_ff2(
    const float* __restrict__ G, const float* __restrict__ W2,
    const float* __restrict__ b2v, float* __restrict__ hs, int row0){
  __shared__ float As[KT][TS+1], Bs[KT][TS+1];
  GEMM_VARS
  float acc[4][4] = {{0}};
  const int mBase=blockIdx.y*TS, nBase=blockIdx.x*TS;
  const float* Ab = G + (size_t)mBase*1280;
  for(int k0=0;k0<1280;k0+=KT){
    #pragma unroll
    for(int i=0;i<4;i++){ int e=tid+i*256; int m=e>>4; int kk=e&15;
      As[kk][m]=Ab[(size_t)m*1280 + k0+kk]; }
    #pragma unroll
    for(int i=0;i<4;i++){ int e=tid+i*256; int kk=e>>6; int nn=e&63;
      Bs[kk][nn]=W2[(size_t)(k0+kk)*QD + nBase+nn]; }
    GEMM_INNER
  }
  #pragma unroll
  for(int i=0;i<4;i++)
    #pragma unroll
    for(int j=0;j<4;j++){
      size_t o=(size_t)(row0+mBase+ty*4+i)*QD + nBase+tx*4+j;
      hs[o] = acc[i][j] + b2v[nBase+tx*4+j] + hs[o];
    }
}

// -------- workspace layout (f32 units): total 17,104,896 fl = 65.25 MiB --------
static const size_t WS_ST  = 0;                    //     65,536  LN stats
static const size_t WS_VM  = 65536;                //    262,144  conv-max
static const size_t WS_KB  = WS_VM + 262144;       //    524,288  k  [1024,512]
static const size_t WS_VB  = WS_KB + 524288;       //    524,288  v
static const size_t WS_VT  = WS_VB + 524288;       //  1,048,576  v_tok [2,1024,512]
static const size_t WS_ATK = WS_VT + 1048576;      //  2,097,152  a_tok chunk [4,1024,512]
static const size_t WS_AKV = WS_ATK + 2097152;     //  2,097,152  agent_kv chunk
static const size_t WS_Q   = WS_AKV + 2097152;     //  2,097,152  q chunk [4096,512]
static const size_t WS_X   = WS_Q   + 2097152;     //  2,097,152  x chunk
static const size_t WS_LG  = WS_X   + 2097152;     //  2,097,152  agent logits [8,1024,256]
static const size_t WS_DQ  = WS_LG  + 2097152;     //  4,194,304  query scores [4,1024,1024]
// end = 17,104,896.  FF G (4096x1280 = 5,242,880) overlays WS_LG..end (6,291,456 avail)
// hs lives in d_out (f32, 10,485,760 elements) for the whole computation.

extern "C" void kernel_launch(void* const* d_in, const int* in_sizes, int n_in,
                              void* d_out, int out_size, void* d_ws, size_t ws_size,
                              hipStream_t stream){
  const float* hidden = (const float*)d_in[0];
  const float* context= (const float*)d_in[1];
  const float* pose   = (const float*)d_in[2];
  const float* Wq  = (const float*)d_in[3];
  const float* Wk  = (const float*)d_in[4];
  const float* Wv  = (const float*)d_in[5];
  const float* Wa  = (const float*)d_in[6];
  const float* abias=(const float*)d_in[7];
  const float* qbias=(const float*)d_in[8];
  const float* dwcw=(const float*)d_in[9];
  const float* dwcb=(const float*)d_in[10];
  const float* Wo  = (const float*)d_in[11];
  const float* nw  = (const float*)d_in[12];
  const float* nb  = (const float*)d_in[13];
  const float* fw  = (const float*)d_in[14];
  const float* fb  = (const float*)d_in[15];
  const float* W1  = (const float*)d_in[16];
  const float* b1  = (const float*)d_in[17];
  const float* W2  = (const float*)d_in[18];
  const float* b2v = (const float*)d_in[19];

  float* ws    = (float*)d_ws;
  float* st    = ws + WS_ST;
  float* vm    = ws + WS_VM;
  float* kb    = ws + WS_KB;
  float* vb    = ws + WS_VB;
  float* vt    = ws + WS_VT;
  float* atokC = ws + WS_ATK;
  float* akvC  = ws + WS_AKV;
  float* qC    = ws + WS_Q;
  float* xC    = ws + WS_X;
  float* lgC   = ws + WS_LG;
  float* Dq    = ws + WS_DQ;

  float* hs = (float*)d_out;   // hs lives in d_out; final FF residual lands in place

  dim3 thr(16,16);
  // hs = hidden  (d2d, 41,943,040 bytes)
  hipMemcpyAsync(hs, hidden, (size_t)B2*TT*NTK*QD*sizeof(float),
                 hipMemcpyDeviceToDevice, stream);

  for(int b=0;b<2;b++){
    // K/V projections: context [1024 x 1024] @ W [1024 x 512]
    k_gemm_ab<<<dim3(8,16),thr,0,stream>>>(context, Wk+(size_t)b*CD*INNR, kb, CD, CD, INNR, INNR);
    k_gemm_ab<<<dim3(8,16),thr,0,stream>>>(context, Wv+(size_t)b*CD*INNR, vb, CD, CD, INNR, INNR);
    // depthwise conv + frame max, bilinear upsample -> v_tok
    k_conv<<<(B2*CTK*INNR)/256,256,0,stream>>>(vb, dwcw+(size_t)b*INNR*9, dwcb+(size_t)b*INNR, vm);
    k_up<<<(B2*NTK*INNR)/256,256,0,stream>>>(vm, vt);
    // LN stats of current hs (used by q projection)
    k_lnstats<<<B2*TT*NTK,64,0,stream>>>(hs, st);
    // process (b2,t) pairs in chunks of 4
    for(int ch=0; ch<8; ch++){
      k_gemm_atok<<<dim3(8,16,4),thr,0,stream>>>(pose, Wa+(size_t)b*QD*INNR, atokC, ch);
      k_logits<<<dim3(4,16,8),thr,0,stream>>>(atokC, kb, abias+(size_t)b*NTK*CTK, lgC, ch);
      k_softmax256<<<8192,256,0,stream>>>(lgC);
      k_pvmax<<<dim3(8,16,4),thr,0,stream>>>(lgC, vb, akvC, ch);
      k_gemm_qln<<<dim3(8,64),thr,0,stream>>>(hs, st, nw, nb, Wq+(size_t)b*QD*INNR, qC, ch*4096);
      k_aql<<<dim3(16,16,4),thr,0,stream>>>(qC, atokC, qbias+(size_t)b*NTK*NTK, Dq);
      k_softmax1024<<<4096,256,0,stream>>>(Dq);
      k_aqpv<<<dim3(8,16,4),thr,0,stream>>>(Dq, akvC, vt, xC, ch);
      k_wo<<<dim3(5,64),thr,0,stream>>>(xC, Wo+(size_t)b*INNR*QD, hs, ch*4096);
    }
  }

  // FF: LN -> GEGLU -> proj, + residual (in place on hs==d_out), 4096-row slices
  k_lnstats<<<B2*TT*NTK,64,0,stream>>>(hs, st);
  float* G = lgC;  // overlays dead lg+Dq region (needs 5,242,880 fl, 6,291,456 avail)
  for(int ch=0; ch<8; ch++){
    k_ff1<<<dim3(20,64),thr,0,stream>>>(hs, st, fw, fb, W1, b1, G, ch*4096);
    k_ff2<<<dim3(5,64),thr,0,stream>>>(G, W2, b2v, hs, ch*4096);
  }
}

// Round 6
// 8227.403 us; speedup vs baseline: 1.2076x; 1.2076x over previous
//
#include <hip/hip_runtime.h>
#include <hip/hip_bf16.h>
#include <math.h>

typedef __hip_bfloat16 bf16;
typedef short short8 __attribute__((ext_vector_type(8)));
typedef float floatx4 __attribute__((ext_vector_type(4)));

// problem constants
static const int B2   = 2;
static const int TT   = 16;
static const int NTK  = 1024;
static const int CTK  = 256;
static const int QD   = 320;
static const int INNR = 512;
static const int CD   = 1024;
#define SCALE_ 0.125f
#define LDK 40   // padded LDS k-stride (bf16 units) for 32-wide k tiles

__device__ __forceinline__ ushort f2bu(float x){
  bf16 h = __float2bfloat16(x);
  return *reinterpret_cast<ushort*>(&h);
}

// ---- stage rows of a row-major f32 matrix into bf16 LDS tile dst[r][k], k0..k0+32 ----
__device__ __forceinline__ void stage_T(ushort* dst, const float* src, int ld, int rows, int tid){
  const int nf4 = rows*8;
  for(int f4=tid; f4<nf4; f4+=256){
    int r = f4>>3, kq = f4&7;
    float4 v = *(const float4*)(src + (size_t)r*ld + kq*4);
    ushort4 u = { f2bu(v.x), f2bu(v.y), f2bu(v.z), f2bu(v.w) };
    *(ushort4*)&dst[r*LDK + kq*4] = u;
  }
}
// ---- stage B[K][N] (NN layout) transposed into bf16 LDS tile dst[n][k] ----
__device__ __forceinline__ void stage_B_nn(ushort* dst, const float* src, int ld, int ncols, int tid){
  const int ne = ncols*32;
  for(int e=tid; e<ne; e+=256){
    int n = e & (ncols-1), kk = e/ncols;
    dst[n*LDK + kk] = f2bu(src[(size_t)kk*ld + n]);
  }
}
// ---- stage LN(hs rows) into bf16 LDS tile ----
__device__ __forceinline__ void stage_ln(ushort* dst, const float* hs, const float* st,
    const float* w, const float* b, int gRowBase, int k0, int tid){
  for(int f4=tid; f4<1024; f4+=256){
    int r = f4>>3, kq = f4&7;
    int gr = gRowBase + r, col = k0 + kq*4;
    float4 h = *(const float4*)(hs + (size_t)gr*QD + col);
    float4 wv= *(const float4*)(w + col);
    float4 bv= *(const float4*)(b + col);
    float mu = st[2*gr], rs = st[2*gr+1];
    ushort4 u = { f2bu((h.x-mu)*rs*wv.x+bv.x), f2bu((h.y-mu)*rs*wv.y+bv.y),
                  f2bu((h.z-mu)*rs*wv.z+bv.z), f2bu((h.w-mu)*rs*wv.w+bv.w) };
    *(ushort4*)&dst[r*LDK + kq*4] = u;
  }
}

template<int NT>
__device__ __forceinline__ void mfma_tiles(const ushort* As, const ushort* Bs,
    floatx4 (&acc)[4][NT], int mOff, int nOff, int lane15, int quad){
  short8 af[4], bfm[NT];
  #pragma unroll
  for(int i=0;i<4;i++) af[i] = *(const short8*)&As[(mOff + i*16 + lane15)*LDK + quad*8];
  #pragma unroll
  for(int j=0;j<NT;j++) bfm[j] = *(const short8*)&Bs[(nOff + j*16 + lane15)*LDK + quad*8];
  #pragma unroll
  for(int i=0;i<4;i++)
    #pragma unroll
    for(int j=0;j<NT;j++)
      acc[i][j] = __builtin_amdgcn_mfma_f32_16x16x32_bf16(af[i], bfm[j], acc[i][j], 0, 0, 0);
}

template<int NT>
__device__ __forceinline__ void zero_acc(floatx4 (&acc)[4][NT]){
  floatx4 z = {0.f,0.f,0.f,0.f};
  #pragma unroll
  for(int i=0;i<4;i++)
    #pragma unroll
    for(int j=0;j<NT;j++) acc[i][j]=z;
}

// NT-GEMM core: A[128 rows][K] row-major, B[BN rows][K] row-major (i.e. B^T), BN = NT*32... BN rows = NT*32? (BN=128 -> NT=4)
template<int NT>
__device__ __forceinline__ void nt_core(const float* Ab, int lda, const float* Bb, int ldb, int K,
    ushort* As, ushort* Bs, floatx4 (&acc)[4][NT], int tid, int mOff, int nOff, int lane15, int quad){
  for(int k0=0;k0<K;k0+=32){
    __syncthreads();
    stage_T(As, Ab + k0, lda, 128, tid);
    stage_T(Bs, Bb + k0, ldb, NT*32, tid);
    __syncthreads();
    mfma_tiles<NT>(As, Bs, acc, mOff, nOff, lane15, quad);
  }
}
// NN-GEMM core: A[128][K] row-major, B[K][N] row-major (Bb pre-offset to col base)
template<int NT>
__device__ __forceinline__ void nn_core(const float* Ab, int lda, const float* Bb, int ldb, int K,
    ushort* As, ushort* Bs, floatx4 (&acc)[4][NT], int tid, int mOff, int nOff, int lane15, int quad){
  for(int k0=0;k0<K;k0+=32){
    __syncthreads();
    stage_T(As, Ab + k0, lda, 128, tid);
    stage_B_nn(Bs, Bb + (size_t)k0*ldb, ldb, NT*32, tid);
    __syncthreads();
    mfma_tiles<NT>(As, Bs, acc, mOff, nOff, lane15, quad);
  }
}

#define GEMM_IDS(NT_) \
  const int tid=threadIdx.x, w=tid>>6, lane15=tid&15, quad=(tid>>4)&3; \
  const int mOff=(w&1)*64, nOff=(w>>1)*(NT_*16);
#define EPI(NT_) \
  _Pragma("unroll") for(int i=0;i<4;i++) \
  _Pragma("unroll") for(int j=0;j<NT_;j++) \
  _Pragma("unroll") for(int r=0;r<4;r++)
#define ROWG (mOff + i*16 + quad*4 + r)
#define COLG (nOff + j*16 + lane15)

// ---------------- kv projection: kb = context @ W  (M=1024,N=512,K=1024) ----------------
__global__ void __launch_bounds__(256) g_kv(const float* __restrict__ A, const float* __restrict__ B,
                                            float* __restrict__ C){
  __shared__ ushort As[128*LDK], Bs[128*LDK];
  GEMM_IDS(4)
  const int rB=blockIdx.y*128, cB=blockIdx.x*128;
  floatx4 acc[4][4]; zero_acc<4>(acc);
  nn_core<4>(A + (size_t)rB*CD, CD, B + cB, INNR, CD, As, Bs, acc, tid, mOff, nOff, lane15, quad);
  EPI(4){ C[(size_t)(rB+ROWG)*INNR + cB+COLG] = acc[i][j][r]; }
}

// ---------------- a_tok: atokC[z] = pose_t[pt] @ Wa  (M=1024,N=512,K=320) ----------------
__global__ void __launch_bounds__(256) g_atok(const float* __restrict__ pose, const float* __restrict__ Wa,
                                              float* __restrict__ atokC, int ch){
  __shared__ ushort As[128*LDK], Bs[128*LDK];
  GEMM_IDS(4)
  const int z=blockIdx.z, pt=ch*4+z, b=pt>>4, t=pt&15;
  const int rB=blockIdx.y*128, cB=blockIdx.x*128;
  floatx4 acc[4][4]; zero_acc<4>(acc);
  for(int k0=0;k0<QD;k0+=32){
    __syncthreads();
    for(int e=tid;e<4096;e+=256){
      int m=e&127, kk=e>>7;
      As[m*LDK+kk] = f2bu(pose[((size_t)(b*QD + k0+kk)*TT + t)*NTK + rB + m]);
    }
    stage_B_nn(Bs, Wa + (size_t)k0*INNR + cB, INNR, 128, tid);
    __syncthreads();
    mfma_tiles<4>(As, Bs, acc, mOff, nOff, lane15, quad);
  }
  EPI(4){ atokC[((size_t)z*NTK + rB+ROWG)*INNR + cB+COLG] = acc[i][j][r]; }
}

// ---------------- agent logits (NT) + scale + bias  (M=1024,N=256,K=512) ----------------
__global__ void __launch_bounds__(256) g_logits(const float* __restrict__ atokC, const float* __restrict__ kbuf,
                                                const float* __restrict__ abias, float* __restrict__ lgC, int ch){
  __shared__ ushort As[128*LDK], Bs[128*LDK];
  GEMM_IDS(4)
  const int z=blockIdx.z, zp=z>>1, c=z&1, pt=ch*4+zp, b=pt>>4;
  const int rB=blockIdx.y*128, cB=blockIdx.x*128;
  floatx4 acc[4][4]; zero_acc<4>(acc);
  nt_core<4>(atokC + ((size_t)zp*NTK + rB)*INNR, INNR,
             kbuf + ((size_t)(b*512 + cB*2 + c))*INNR, 2*INNR, INNR,
             As, Bs, acc, tid, mOff, nOff, lane15, quad);
  float* Cz = lgC + (size_t)(zp*2+c)*NTK*CTK;
  EPI(4){
    int row=rB+ROWG, col=cB+COLG;
    Cz[(size_t)row*CTK + col] = acc[i][j][r]*SCALE_ + abias[(size_t)row*CTK + col];
  }
}

// ---------------- PV + frame max (NN x2)  (M=1024,N=512,K=256) ----------------
__global__ void __launch_bounds__(256) g_pvmax(const float* __restrict__ lgC, const float* __restrict__ vbuf,
                                               float* __restrict__ akvC, int ch){
  __shared__ ushort As[128*LDK], Bs[128*LDK];
  GEMM_IDS(4)
  const int zp=blockIdx.z, pt=ch*4+zp, b=pt>>4;
  const int rB=blockIdx.y*128, cB=blockIdx.x*128;
  floatx4 best[4][4]; zero_acc<4>(best);
  floatx4 acc[4][4];
  for(int c=0;c<2;c++){
    zero_acc<4>(acc);
    nn_core<4>(lgC + ((size_t)(zp*2+c)*NTK + rB)*CTK, CTK,
               vbuf + (size_t)(b*2+c)*CTK*INNR + cB, INNR, CTK,
               As, Bs, acc, tid, mOff, nOff, lane15, quad);
    if(c==0){
      #pragma unroll
      for(int i=0;i<4;i++)
        #pragma unroll
        for(int j=0;j<4;j++) best[i][j]=acc[i][j];
    }else{
      EPI(4){ best[i][j][r] = fmaxf(best[i][j][r], acc[i][j][r]); }
    }
  }
  EPI(4){ akvC[((size_t)zp*NTK + rB+ROWG)*INNR + cB+COLG] = best[i][j][r]; }
}

// ---------------- q = LN(hs) @ Wq  (M=4096/chunk,N=512,K=320) ----------------
__global__ void __launch_bounds__(256) g_qln(const float* __restrict__ hs, const float* __restrict__ st,
    const float* __restrict__ nw, const float* __restrict__ nb,
    const float* __restrict__ Wq, float* __restrict__ qC, int row0){
  __shared__ ushort As[128*LDK], Bs[128*LDK];
  GEMM_IDS(4)
  const int rB=blockIdx.y*128, cB=blockIdx.x*128;
  floatx4 acc[4][4]; zero_acc<4>(acc);
  for(int k0=0;k0<QD;k0+=32){
    __syncthreads();
    stage_ln(As, hs, st, nw, nb, row0+rB, k0, tid);
    stage_B_nn(Bs, Wq + (size_t)k0*INNR + cB, INNR, 128, tid);
    __syncthreads();
    mfma_tiles<4>(As, Bs, acc, mOff, nOff, lane15, quad);
  }
  EPI(4){ qC[(size_t)(rB+ROWG)*INNR + cB+COLG] = acc[i][j][r]; }
}

// ---------------- query logits (NT) + scale + qbias  (M=1024,N=1024,K=512) ----------------
__global__ void __launch_bounds__(256) g_aql(const float* __restrict__ qC, const float* __restrict__ atokC,
                                             const float* __restrict__ qbias, float* __restrict__ D){
  __shared__ ushort As[128*LDK], Bs[128*LDK];
  GEMM_IDS(4)
  const int z=blockIdx.z;
  const int rB=blockIdx.y*128, cB=blockIdx.x*128;
  floatx4 acc[4][4]; zero_acc<4>(acc);
  nt_core<4>(qC + ((size_t)z*NTK + rB)*INNR, INNR,
             atokC + ((size_t)z*NTK + cB)*INNR, INNR, INNR,
             As, Bs, acc, tid, mOff, nOff, lane15, quad);
  float* Dz = D + (size_t)z*NTK*NTK;
  EPI(4){
    int row=rB+ROWG, col=cB+COLG;
    Dz[(size_t)row*NTK + col] = acc[i][j][r]*SCALE_ + qbias[(size_t)row*NTK + col];
  }
}

// ---------------- x = aq @ akv + v_tok (NN)  (M=1024,N=512,K=1024) ----------------
__global__ void __launch_bounds__(256) g_aqpv(const float* __restrict__ D, const float* __restrict__ akvC,
                                              const float* __restrict__ vt, float* __restrict__ xC, int ch){
  __shared__ ushort As[128*LDK], Bs[128*LDK];
  GEMM_IDS(4)
  const int z=blockIdx.z, pt=ch*4+z, b=pt>>4;
  const int rB=blockIdx.y*128, cB=blockIdx.x*128;
  floatx4 acc[4][4]; zero_acc<4>(acc);
  nn_core<4>(D + ((size_t)z*NTK + rB)*NTK, NTK,
             akvC + (size_t)z*NTK*INNR + cB, INNR, NTK,
             As, Bs, acc, tid, mOff, nOff, lane15, quad);
  EPI(4){
    int row=rB+ROWG, col=cB+COLG;
    xC[((size_t)z*NTK + row)*INNR + col] = acc[i][j][r] + vt[((size_t)b*NTK + row)*INNR + col];
  }
}

// ---------------- hs += x @ Wo (NN, BN=64)  (M=4096,N=320,K=512) ----------------
__global__ void __launch_bounds__(256) g_wo(const float* __restrict__ xC, const float* __restrict__ Wo,
                                            float* __restrict__ hs, int row0){
  __shared__ ushort As[128*LDK], Bs[64*LDK];
  GEMM_IDS(2)
  const int rB=blockIdx.y*128, cB=blockIdx.x*64;
  floatx4 acc[4][2]; zero_acc<2>(acc);
  nn_core<2>(xC + (size_t)rB*INNR, INNR, Wo + cB, QD, INNR,
             As, Bs, acc, tid, mOff, nOff, lane15, quad);
  EPI(2){
    size_t o = (size_t)(row0+rB+ROWG)*QD + cB+COLG;
    hs[o] = hs[o] + acc[i][j][r];
  }
}

// ---------------- FF1 GEGLU (NN dual-B, BN=64)  (M=4096,N=1280,K=320) ----------------
__global__ void __launch_bounds__(256) g_ff1(const float* __restrict__ hs, const float* __restrict__ st,
    const float* __restrict__ lw, const float* __restrict__ lb,
    const float* __restrict__ W1, const float* __restrict__ b1,
    float* __restrict__ G, int row0){
  __shared__ ushort As[128*LDK], Ba[64*LDK], Bg[64*LDK];
  GEMM_IDS(2)
  const int rB=blockIdx.y*128, cB=blockIdx.x*64;
  floatx4 accA[4][2], accG[4][2]; zero_acc<2>(accA); zero_acc<2>(accG);
  for(int k0=0;k0<QD;k0+=32){
    __syncthreads();
    stage_ln(As, hs, st, lw, lb, row0+rB, k0, tid);
    stage_B_nn(Ba, W1 + (size_t)k0*2560 + cB, 2560, 64, tid);
    stage_B_nn(Bg, W1 + (size_t)k0*2560 + 1280 + cB, 2560, 64, tid);
    __syncthreads();
    mfma_tiles<2>(As, Ba, accA, mOff, nOff, lane15, quad);
    mfma_tiles<2>(As, Bg, accG, mOff, nOff, lane15, quad);
  }
  EPI(2){
    int n = cB+COLG;
    float a = accA[i][j][r] + b1[n];
    float g = accG[i][j][r] + b1[1280+n];
    G[(size_t)(rB+ROWG)*1280 + n] = a*0.5f*g*(1.0f+erff(g*0.70710678f));
  }
}

// ---------------- FF2 (NN, BN=64) + bias + residual  (M=4096,N=320,K=1280) ----------------
__global__ void __launch_bounds__(256) g_ff2(const float* __restrict__ G, const float* __restrict__ W2,
    const float* __restrict__ b2v, float* __restrict__ hs, int row0){
  __shared__ ushort As[128*LDK], Bs[64*LDK];
  GEMM_IDS(2)
  const int rB=blockIdx.y*128, cB=blockIdx.x*64;
  floatx4 acc[4][2]; zero_acc<2>(acc);
  nn_core<2>(G + (size_t)rB*1280, 1280, W2 + cB, QD, 1280,
             As, Bs, acc, tid, mOff, nOff, lane15, quad);
  EPI(2){
    int col = cB+COLG;
    size_t o = (size_t)(row0+rB+ROWG)*QD + col;
    hs[o] = acc[i][j][r] + b2v[col] + hs[o];
  }
}

// ---------------- softmax over rows of 256 ----------------
__global__ void k_softmax256(float* __restrict__ buf){
  __shared__ float red[8];
  const int tid=threadIdx.x;
  size_t row=blockIdx.x;
  float x = buf[row*256+tid];
  float m = x;
  #pragma unroll
  for(int o=32;o;o>>=1) m=fmaxf(m,__shfl_down(m,o));
  if((tid&63)==0) red[tid>>6]=m;
  __syncthreads();
  if(tid==0) red[4]=fmaxf(fmaxf(red[0],red[1]),fmaxf(red[2],red[3]));
  __syncthreads();
  float M=red[4];
  float e=__expf(x-M);
  float s=e;
  #pragma unroll
  for(int o=32;o;o>>=1) s+=__shfl_down(s,o);
  if((tid&63)==0) red[tid>>6]=s;
  __syncthreads();
  if(tid==0) red[5]=red[0]+red[1]+red[2]+red[3];
  __syncthreads();
  buf[row*256+tid] = e/red[5];
}

// ---------------- softmax over rows of 1024 ----------------
__global__ void k_softmax1024(float* __restrict__ buf){
  __shared__ float red[8];
  const int tid=threadIdx.x;
  size_t row=blockIdx.x;
  float4* p = (float4*)(buf + row*1024);
  float4 v = p[tid];
  float m = fmaxf(fmaxf(v.x,v.y),fmaxf(v.z,v.w));
  #pragma unroll
  for(int o=32;o;o>>=1) m=fmaxf(m,__shfl_down(m,o));
  if((tid&63)==0) red[tid>>6]=m;
  __syncthreads();
  if(tid==0) red[4]=fmaxf(fmaxf(red[0],red[1]),fmaxf(red[2],red[3]));
  __syncthreads();
  float M=red[4];
  v.x=__expf(v.x-M); v.y=__expf(v.y-M); v.z=__expf(v.z-M); v.w=__expf(v.w-M);
  float s=v.x+v.y+v.z+v.w;
  #pragma unroll
  for(int o=32;o;o>>=1) s+=__shfl_down(s,o);
  if((tid&63)==0) red[tid>>6]=s;
  __syncthreads();
  if(tid==0) red[5]=red[0]+red[1]+red[2]+red[3];
  __syncthreads();
  float inv=1.0f/red[5];
  v.x*=inv; v.y*=inv; v.z*=inv; v.w*=inv;
  p[tid]=v;
}

// ---------------- depthwise 3x3 conv (SAME) + max over frames ----------------
__global__ void k_conv(const float* __restrict__ vbuf, const float* __restrict__ w3,
                       const float* __restrict__ wb, float* __restrict__ vm){
  int idx = blockIdx.x*256+threadIdx.x;
  if(idx >= B2*CTK*INNR) return;
  int e = idx & 511, hw = (idx>>9)&255, b = idx>>17;
  int h = hw>>4, w = hw&15;
  float wt[9];
  #pragma unroll
  for(int q=0;q<9;q++) wt[q]=w3[e*9+q];
  float bias = wb[e];
  float best=0.f;
  for(int c=0;c<2;c++){
    float s = bias;
    #pragma unroll
    for(int dy=-1;dy<=1;dy++)
      #pragma unroll
      for(int dx=-1;dx<=1;dx++){
        int hh=h+dy, ww=w+dx;
        if(hh>=0&&hh<16&&ww>=0&&ww<16)
          s += wt[(dy+1)*3+(dx+1)]*vbuf[((size_t)(b*2+c)*CTK + hh*16+ww)*INNR + e];
      }
    best = c ? fmaxf(best,s) : s;
  }
  vm[((size_t)b*CTK + hw)*INNR + e] = best;
}

// ---------------- bilinear x2 upsample (half-pixel, edge clamp) ----------------
__device__ __forceinline__ void up_wt(int i, int& j0, int& j1, float& w){
  float s = 0.5f*i - 0.25f;
  float f = floorf(s);
  w = s - f;
  int a = (int)f;
  j0 = min(15, max(0, a));
  j1 = min(15, max(0, a+1));
}
__global__ void k_up(const float* __restrict__ vm, float* __restrict__ vt){
  int idx = blockIdx.x*256+threadIdx.x;
  if(idx >= B2*NTK*INNR) return;
  int e = idx & 511, n = (idx>>9)&1023, b = idx>>19;
  int hm = n>>5, wm = n&31;
  int h0,h1,w0,w1; float fh,fw;
  up_wt(hm,h0,h1,fh); up_wt(wm,w0,w1,fw);
  const float* base = vm + (size_t)b*CTK*INNR + e;
  float v00=base[(size_t)(h0*16+w0)*INNR], v01=base[(size_t)(h0*16+w1)*INNR];
  float v10=base[(size_t)(h1*16+w0)*INNR], v11=base[(size_t)(h1*16+w1)*INNR];
  vt[((size_t)b*NTK+n)*INNR+e] = (1.f-fh)*((1.f-fw)*v00+fw*v01) + fh*((1.f-fw)*v10+fw*v11);
}

// ---------------- LayerNorm row stats ----------------
__global__ void k_lnstats(const float* __restrict__ hs, float* __restrict__ st){
  size_t r = blockIdx.x;
  int lane = threadIdx.x;
  float s=0.f, s2=0.f;
  #pragma unroll
  for(int j=0;j<5;j++){ float v=hs[r*QD + j*64 + lane]; s+=v; s2+=v*v; }
  #pragma unroll
  for(int o=32;o;o>>=1){ s+=__shfl_down(s,o); s2+=__shfl_down(s2,o); }
  if(lane==0){
    float mu=s*(1.f/320.f);
    float var=s2*(1.f/320.f)-mu*mu;
    st[2*r]=mu; st[2*r+1]=rsqrtf(var+1e-5f);
  }
}

// -------- workspace layout (f32 units): total 17,104,896 fl = 65.25 MiB (proven safe) --------
static const size_t WS_ST  = 0;
static const size_t WS_VM  = 65536;
static const size_t WS_KB  = WS_VM + 262144;
static const size_t WS_VB  = WS_KB + 524288;
static const size_t WS_VT  = WS_VB + 524288;
static const size_t WS_ATK = WS_VT + 1048576;
static const size_t WS_AKV = WS_ATK + 2097152;
static const size_t WS_Q   = WS_AKV + 2097152;
static const size_t WS_X   = WS_Q   + 2097152;
static const size_t WS_LG  = WS_X   + 2097152;
static const size_t WS_DQ  = WS_LG  + 2097152;
// FF G (4096x1280) overlays WS_LG..end. hs lives in d_out (f32).

extern "C" void kernel_launch(void* const* d_in, const int* in_sizes, int n_in,
                              void* d_out, int out_size, void* d_ws, size_t ws_size,
                              hipStream_t stream){
  const float* hidden = (const float*)d_in[0];
  const float* context= (const float*)d_in[1];
  const float* pose   = (const float*)d_in[2];
  const float* Wq  = (const float*)d_in[3];
  const float* Wk  = (const float*)d_in[4];
  const float* Wv  = (const float*)d_in[5];
  const float* Wa  = (const float*)d_in[6];
  const float* abias=(const float*)d_in[7];
  const float* qbias=(const float*)d_in[8];
  const float* dwcw=(const float*)d_in[9];
  const float* dwcb=(const float*)d_in[10];
  const float* Wo  = (const float*)d_in[11];
  const float* nw  = (const float*)d_in[12];
  const float* nb  = (const float*)d_in[13];
  const float* fw  = (const float*)d_in[14];
  const float* fb  = (const float*)d_in[15];
  const float* W1  = (const float*)d_in[16];
  const float* b1  = (const float*)d_in[17];
  const float* W2  = (const float*)d_in[18];
  const float* b2v = (const float*)d_in[19];

  float* ws    = (float*)d_ws;
  float* st    = ws + WS_ST;
  float* vm    = ws + WS_VM;
  float* kb    = ws + WS_KB;
  float* vb    = ws + WS_VB;
  float* vt    = ws + WS_VT;
  float* atokC = ws + WS_ATK;
  float* akvC  = ws + WS_AKV;
  float* qC    = ws + WS_Q;
  float* xC    = ws + WS_X;
  float* lgC   = ws + WS_LG;
  float* Dq    = ws + WS_DQ;

  float* hs = (float*)d_out;

  hipMemcpyAsync(hs, hidden, (size_t)B2*TT*NTK*QD*sizeof(float),
                 hipMemcpyDeviceToDevice, stream);

  for(int b=0;b<2;b++){
    g_kv<<<dim3(4,8),256,0,stream>>>(context, Wk+(size_t)b*CD*INNR, kb);
    g_kv<<<dim3(4,8),256,0,stream>>>(context, Wv+(size_t)b*CD*INNR, vb);
    k_conv<<<(B2*CTK*INNR)/256,256,0,stream>>>(vb, dwcw+(size_t)b*INNR*9, dwcb+(size_t)b*INNR, vm);
    k_up<<<(B2*NTK*INNR)/256,256,0,stream>>>(vm, vt);
    k_lnstats<<<B2*TT*NTK,64,0,stream>>>(hs, st);
    for(int ch=0; ch<8; ch++){
      g_atok<<<dim3(4,8,4),256,0,stream>>>(pose, Wa+(size_t)b*QD*INNR, atokC, ch);
      g_logits<<<dim3(2,8,8),256,0,stream>>>(atokC, kb, abias+(size_t)b*NTK*CTK, lgC, ch);
      k_softmax256<<<8192,256,0,stream>>>(lgC);
      g_pvmax<<<dim3(4,8,4),256,0,stream>>>(lgC, vb, akvC, ch);
      g_qln<<<dim3(4,32),256,0,stream>>>(hs, st, nw, nb, Wq+(size_t)b*QD*INNR, qC, ch*4096);
      g_aql<<<dim3(8,8,4),256,0,stream>>>(qC, atokC, qbias+(size_t)b*NTK*NTK, Dq);
      k_softmax1024<<<4096,256,0,stream>>>(Dq);
      g_aqpv<<<dim3(4,8,4),256,0,stream>>>(Dq, akvC, vt, xC, ch);
      g_wo<<<dim3(5,32),256,0,stream>>>(xC, Wo+(size_t)b*INNR*QD, hs, ch*4096);
    }
  }

  k_lnstats<<<B2*TT*NTK,64,0,stream>>>(hs, st);
  float* G = lgC;
  for(int ch=0; ch<8; ch++){
    g_ff1<<<dim3(20,32),256,0,stream>>>(hs, st, fw, fb, W1, b1, G, ch*4096);
    g_ff2<<<dim3(5,32),256,0,stream>>>(G, W2, b2v, hs, ch*4096);
  }
}